// Round 1
// baseline (25865.753 us; speedup 1.0000x reference)
//
#include <hip/hip_runtime.h>
#include <stdint.h>

// LSTM: B=64, T=512, I=H=1024. bf16 MFMA path.
// Phase 1: Xg = x @ Wih^T + b  (big GEMM, m97-style 128x128 tiles, permuted col layout)
// Phase 2: persistent 256-block kernel, 512 steps, grid barrier per step.

typedef __bf16 bf16x8 __attribute__((ext_vector_type(8)));
typedef float f32x4 __attribute__((ext_vector_type(4)));

#define BATCH 64
#define TSEQ 512
#define HID 1024
#define MROWS (BATCH * TSEQ)  // 32768
#define NGATE 4096

__device__ __forceinline__ unsigned short f2bf(float f) {
  union { float f; unsigned u; } v; v.f = f;
  unsigned r = (v.u + 0x7FFFu + ((v.u >> 16) & 1u)) >> 16;
  return (unsigned short)r;
}
__device__ __forceinline__ float bf2f(unsigned short u) {
  union { unsigned u; float f; } v; v.u = ((unsigned)u) << 16;
  return v.f;
}

__global__ void cvt_kernel(const float* __restrict__ src,
                           unsigned short* __restrict__ dst, int n4) {
  int i = blockIdx.x * blockDim.x + threadIdx.x;
  const int stride = gridDim.x * blockDim.x;
  for (; i < n4; i += stride) {
    float4 f = ((const float4*)src)[i];
    ushort4 u;
    u.x = f2bf(f.x); u.y = f2bf(f.y); u.z = f2bf(f.z); u.w = f2bf(f.w);
    ((ushort4*)dst)[i] = u;
  }
}

__device__ __forceinline__ void gl_lds16(const unsigned short* g, unsigned short* lds) {
  __builtin_amdgcn_global_load_lds(
      (const __attribute__((address_space(1))) unsigned int*)g,
      (__attribute__((address_space(3))) unsigned int*)lds, 16, 0, 0);
}

// ---------------- Phase 1 GEMM: Xg[r][perm(n)] = sum_k x[r][k]*Wih[n][k] + b[n]
// perm(n) = ((n&1023)>>4)*64 + (n>>10)*16 + (n&15): block bn of phase 2 reads
// 128B contiguous per row.
__global__ __launch_bounds__(256, 2) void gemm_xg(
    const unsigned short* __restrict__ A,   // x_bf   [32768][1024]
    const unsigned short* __restrict__ B,   // Wih_bf [4096][1024]
    const float* __restrict__ bias,         // [4096]
    unsigned short* __restrict__ Xg)        // [32768][4096] permuted cols
{
  __shared__ __align__(16) unsigned short Asm[128 * 32];  // 8 KB, swizzled
  __shared__ __align__(16) unsigned short Bsm[128 * 32];
  const int tid = threadIdx.x;
  const int lane = tid & 63;
  const int wave = tid >> 6;
  const int row0 = blockIdx.y * 128;
  const int col0 = blockIdx.x * 128;
  const int wm = (wave >> 1) * 64;
  const int wn = (wave & 1) * 64;
  // staging lane mapping (XOR swizzle at 16B granularity -> 2-way banks on read = free)
  const int s_ml = lane >> 2;
  const int s_q = ((lane & 3) ^ (s_ml >> 1)) & 3;
  const int fm = lane & 15;
  const int fq = lane >> 4;
  const int swz = ((fq ^ (fm >> 1)) & 3) * 8;

  f32x4 acc[4][4] = {};

  for (int kt = 0; kt < 32; ++kt) {
    const int k0 = kt * 32;
    __syncthreads();
#pragma unroll
    for (int gI = 0; gI < 2; ++gI) {
      const int grp = wave * 2 + gI;
      const unsigned short* ga =
          A + (size_t)(row0 + grp * 16 + s_ml) * 1024 + k0 + s_q * 8;
      gl_lds16(ga, &Asm[grp * 512]);
      const unsigned short* gb =
          B + (size_t)(col0 + grp * 16 + s_ml) * 1024 + k0 + s_q * 8;
      gl_lds16(gb, &Bsm[grp * 512]);
    }
    __syncthreads();
    bf16x8 af[4], bfv[4];
#pragma unroll
    for (int mt = 0; mt < 4; ++mt) {
      const int m = wm + mt * 16 + fm;
      af[mt] = *(const bf16x8*)&Asm[(m >> 4) * 512 + fm * 32 + swz];
    }
#pragma unroll
    for (int nt = 0; nt < 4; ++nt) {
      const int n = wn + nt * 16 + fm;
      bfv[nt] = *(const bf16x8*)&Bsm[(n >> 4) * 512 + fm * 32 + swz];
    }
#pragma unroll
    for (int mt = 0; mt < 4; ++mt)
#pragma unroll
      for (int nt = 0; nt < 4; ++nt)
        acc[mt][nt] = __builtin_amdgcn_mfma_f32_16x16x32_bf16(
            af[mt], bfv[nt], acc[mt][nt], 0, 0, 0);
  }
  // epilogue: permuted column store, bias add, bf16
#pragma unroll
  for (int nt = 0; nt < 4; ++nt) {
    const int nb = col0 + wn + nt * 16;
    const int pbase = ((nb & 1023) >> 4) * 64 + (nb >> 10) * 16;
    const float bv = bias[nb + fm];
#pragma unroll
    for (int mt = 0; mt < 4; ++mt) {
#pragma unroll
      for (int r = 0; r < 4; ++r) {
        const int row = row0 + wm + mt * 16 + fq * 4 + r;
        Xg[(size_t)row * 4096 + pbase + fm] = f2bf(acc[mt][nt][r] + bv);
      }
    }
  }
}

// ---------------- Phase 2: persistent recurrence.
// 256 blocks: bn = blockIdx>>2 (hidden slice of 16), mi = blockIdx&3 (16 batch rows).
// Wave w holds Whh B-frags for its K-quarter in 128 VGPRs. c in registers.
__global__ __launch_bounds__(256, 1) void lstm_seq(
    const unsigned short* __restrict__ Whh,  // [4096][1024] bf16
    const unsigned short* __restrict__ Xg,   // [32768][4096] bf16 permuted
    float* __restrict__ out,
    unsigned short* __restrict__ hbuf,       // 2 x [64][1024] bf16 ping-pong
    unsigned int* __restrict__ counter)
{
  __shared__ float part[4][16][68];     // [wave][m][4*16 cols], +4 pad -> 2-way banks
  __shared__ float pad_lds[20480];      // 80 KB: force 1 block/CU (co-residency)
  const int tid = threadIdx.x;
  const int lane = tid & 63;
  const int wave = tid >> 6;
  const int bn = blockIdx.x >> 2;
  const int mi = blockIdx.x & 3;
  const int fm = lane & 15;
  const int fq = lane >> 4;
  if (tid == 0) pad_lds[0] = 0.f;  // keep allocation live

  // Load persistent B-frags: bfrag[gate][ki] = Whh[n][k], n=gate*1024+bn*16+fm,
  // k = wave*256 + ki*32 + fq*8 .. +8
  bf16x8 bfrag[4][8];
#pragma unroll
  for (int g = 0; g < 4; ++g) {
    const unsigned short* wrow =
        Whh + (size_t)(g * 1024 + bn * 16 + fm) * 1024 + wave * 256 + fq * 8;
#pragma unroll
    for (int ki = 0; ki < 8; ++ki) bfrag[g][ki] = *(const bf16x8*)(wrow + ki * 32);
  }

  const int em = tid >> 4, ej = tid & 15;   // elementwise: (batch-local, hidden-local)
  const int gb = mi * 16 + em;              // global batch row
  const int gj = bn * 16 + ej;              // global hidden index
  float c_reg = 0.f;

  unsigned short* h0 = hbuf;
  unsigned short* h1 = hbuf + BATCH * HID;

  for (int t = 0; t < TSEQ; ++t) {
    const unsigned short* hp = (t & 1) ? h1 : h0;
    unsigned short* hn = (t & 1) ? h0 : h1;

    f32x4 acc[4] = {};
    const unsigned short* ab =
        hp + (size_t)(mi * 16 + fm) * 1024 + wave * 256 + fq * 8;
#pragma unroll
    for (int ki = 0; ki < 8; ++ki) {
      bf16x8 a = *(const bf16x8*)(ab + ki * 32);
#pragma unroll
      for (int g = 0; g < 4; ++g)
        acc[g] = __builtin_amdgcn_mfma_f32_16x16x32_bf16(a, bfrag[g][ki], acc[g], 0, 0, 0);
    }
#pragma unroll
    for (int g = 0; g < 4; ++g)
#pragma unroll
      for (int r = 0; r < 4; ++r)
        part[wave][fq * 4 + r][g * 16 + fm] = acc[g][r];
    __syncthreads();

    // K-reduce over 4 waves + Xg + elementwise (each thread: 1 (b,j) cell)
    const unsigned short* xr = Xg + ((size_t)gb * TSEQ + t) * 4096 + bn * 64;
    float gate[4];
#pragma unroll
    for (int g = 0; g < 4; ++g) {
      float s = part[0][em][g * 16 + ej] + part[1][em][g * 16 + ej] +
                part[2][em][g * 16 + ej] + part[3][em][g * 16 + ej];
      gate[g] = s + bf2f(xr[g * 16 + ej]);
    }
    const float ig = 1.f / (1.f + __expf(-gate[0]));
    const float fg = 1.f / (1.f + __expf(-gate[1]));
    const float gg = 1.f - 2.f / (__expf(2.f * gate[2]) + 1.f);  // tanh, inf-safe
    const float og = 1.f / (1.f + __expf(-gate[3]));
    c_reg = fg * c_reg + ig * gg;
    const float th = 1.f - 2.f / (__expf(2.f * c_reg) + 1.f);
    const float hv = og * th;

    hn[(size_t)gb * HID + gj] = f2bf(hv);
    out[((size_t)gb * TSEQ + t) * HID + gj] = hv;
    if (t == TSEQ - 1) {
      out[(size_t)BATCH * TSEQ * HID + (size_t)gb * HID + gj] = hv;
      out[(size_t)BATCH * TSEQ * HID + (size_t)BATCH * HID + (size_t)gb * HID + gj] = c_reg;
    }

    // grid barrier: release h stores (cross-XCD), arrive, spin, acquire
    __threadfence();
    __syncthreads();
    if (tid == 0) {
      __hip_atomic_fetch_add(counter, 1u, __ATOMIC_RELEASE, __HIP_MEMORY_SCOPE_AGENT);
      const unsigned target = 256u * (unsigned)(t + 1);
      while (__hip_atomic_load(counter, __ATOMIC_ACQUIRE, __HIP_MEMORY_SCOPE_AGENT) < target)
        __builtin_amdgcn_s_sleep(2);
    }
    __syncthreads();
    __threadfence();
  }
}

extern "C" void kernel_launch(void* const* d_in, const int* in_sizes, int n_in,
                              void* d_out, int out_size, void* d_ws, size_t ws_size,
                              hipStream_t stream) {
  (void)in_sizes; (void)n_in; (void)out_size;
  const float* x   = (const float*)d_in[0];
  const float* Wih = (const float*)d_in[1];
  const float* Whh = (const float*)d_in[2];
  const float* b   = (const float*)d_in[3];
  float* out = (float*)d_out;

  char* ws = (char*)d_ws;
  // ws layout (256-aligned offsets)
  unsigned int* counter  = (unsigned int*)ws;                         // 256 B
  unsigned short* hbuf   = (unsigned short*)(ws + 256);               // 256 KB
  unsigned short* x_bf   = (unsigned short*)(ws + 262400);            // 64 MB
  unsigned short* wih_bf = (unsigned short*)(ws + 262400 + 67108864); // 8 MB
  unsigned short* whh_bf = (unsigned short*)(ws + 262400 + 75497472); // 8 MB
  unsigned short* xg     = (unsigned short*)(ws + 262400 + 83886080); // 256 MB
  const size_t needed = 262400ULL + 83886080ULL + 268435456ULL;       // ~337 MB
  if (ws_size < needed) return;  // workspace too small: fail visibly (zero output)

  hipMemsetAsync(counter, 0, 256, stream);
  hipMemsetAsync(hbuf, 0, 2 * BATCH * HID * sizeof(unsigned short), stream);

  cvt_kernel<<<2048, 256, 0, stream>>>(x, x_bf, (MROWS * 1024) / 4);
  cvt_kernel<<<512, 256, 0, stream>>>(Wih, wih_bf, (NGATE * 1024) / 4);
  cvt_kernel<<<512, 256, 0, stream>>>(Whh, whh_bf, (NGATE * 1024) / 4);

  dim3 g(32, 256);  // (n-tiles, m-tiles)
  gemm_xg<<<g, 256, 0, stream>>>(x_bf, wih_bf, b, xg);

  lstm_seq<<<256, 256, 0, stream>>>(whh_bf, xg, out, hbuf, counter);
}

// Round 2
// 4468.303 us; speedup vs baseline: 5.7887x; 5.7887x over previous
//
#include <hip/hip_runtime.h>
#include <stdint.h>

// LSTM: B=64, T=512, I=H=1024. bf16 MFMA path.
// Phase 1: Xg = x @ Wih^T + b  (m97-style 128x128 tile GEMM, permuted col layout)
// Phase 2: persistent 256-block kernel, 512 steps, per-batch-group grid barrier.
// R1: barrier rework — relaxed polling + single acquire, per-mi-group counters,
//     Xg register prefetch across the barrier.

typedef __bf16 bf16x8 __attribute__((ext_vector_type(8)));
typedef float f32x4 __attribute__((ext_vector_type(4)));

#define BATCH 64
#define TSEQ 512
#define HID 1024
#define MROWS (BATCH * TSEQ)  // 32768
#define NGATE 4096

__device__ __forceinline__ unsigned short f2bf(float f) {
  union { float f; unsigned u; } v; v.f = f;
  unsigned r = (v.u + 0x7FFFu + ((v.u >> 16) & 1u)) >> 16;
  return (unsigned short)r;
}
__device__ __forceinline__ float bf2f(unsigned short u) {
  union { unsigned u; float f; } v; v.u = ((unsigned)u) << 16;
  return v.f;
}

__global__ void cvt_kernel(const float* __restrict__ src,
                           unsigned short* __restrict__ dst, int n4) {
  int i = blockIdx.x * blockDim.x + threadIdx.x;
  const int stride = gridDim.x * blockDim.x;
  for (; i < n4; i += stride) {
    float4 f = ((const float4*)src)[i];
    ushort4 u;
    u.x = f2bf(f.x); u.y = f2bf(f.y); u.z = f2bf(f.z); u.w = f2bf(f.w);
    ((ushort4*)dst)[i] = u;
  }
}

__device__ __forceinline__ void gl_lds16(const unsigned short* g, unsigned short* lds) {
  __builtin_amdgcn_global_load_lds(
      (const __attribute__((address_space(1))) unsigned int*)g,
      (__attribute__((address_space(3))) unsigned int*)lds, 16, 0, 0);
}

// ---------------- Phase 1 GEMM: Xg[r][perm(n)] = sum_k x[r][k]*Wih[n][k] + b[n]
// perm(n) = ((n&1023)>>4)*64 + (n>>10)*16 + (n&15): block bn of phase 2 reads
// 128B contiguous per row.
__global__ __launch_bounds__(256, 2) void gemm_xg(
    const unsigned short* __restrict__ A,   // x_bf   [32768][1024]
    const unsigned short* __restrict__ B,   // Wih_bf [4096][1024]
    const float* __restrict__ bias,         // [4096]
    unsigned short* __restrict__ Xg)        // [32768][4096] permuted cols
{
  __shared__ __align__(16) unsigned short Asm[128 * 32];  // 8 KB, swizzled
  __shared__ __align__(16) unsigned short Bsm[128 * 32];
  const int tid = threadIdx.x;
  const int lane = tid & 63;
  const int wave = tid >> 6;
  const int row0 = blockIdx.y * 128;
  const int col0 = blockIdx.x * 128;
  const int wm = (wave >> 1) * 64;
  const int wn = (wave & 1) * 64;
  const int s_ml = lane >> 2;
  const int s_q = ((lane & 3) ^ (s_ml >> 1)) & 3;
  const int fm = lane & 15;
  const int fq = lane >> 4;
  const int swz = ((fq ^ (fm >> 1)) & 3) * 8;

  f32x4 acc[4][4] = {};

  for (int kt = 0; kt < 32; ++kt) {
    const int k0 = kt * 32;
    __syncthreads();
#pragma unroll
    for (int gI = 0; gI < 2; ++gI) {
      const int grp = wave * 2 + gI;
      const unsigned short* ga =
          A + (size_t)(row0 + grp * 16 + s_ml) * 1024 + k0 + s_q * 8;
      gl_lds16(ga, &Asm[grp * 512]);
      const unsigned short* gb =
          B + (size_t)(col0 + grp * 16 + s_ml) * 1024 + k0 + s_q * 8;
      gl_lds16(gb, &Bsm[grp * 512]);
    }
    __syncthreads();
    bf16x8 af[4], bfv[4];
#pragma unroll
    for (int mt = 0; mt < 4; ++mt) {
      const int m = wm + mt * 16 + fm;
      af[mt] = *(const bf16x8*)&Asm[(m >> 4) * 512 + fm * 32 + swz];
    }
#pragma unroll
    for (int nt = 0; nt < 4; ++nt) {
      const int n = wn + nt * 16 + fm;
      bfv[nt] = *(const bf16x8*)&Bsm[(n >> 4) * 512 + fm * 32 + swz];
    }
#pragma unroll
    for (int mt = 0; mt < 4; ++mt)
#pragma unroll
      for (int nt = 0; nt < 4; ++nt)
        acc[mt][nt] = __builtin_amdgcn_mfma_f32_16x16x32_bf16(
            af[mt], bfv[nt], acc[mt][nt], 0, 0, 0);
  }
#pragma unroll
  for (int nt = 0; nt < 4; ++nt) {
    const int nb = col0 + wn + nt * 16;
    const int pbase = ((nb & 1023) >> 4) * 64 + (nb >> 10) * 16;
    const float bv = bias[nb + fm];
#pragma unroll
    for (int mt = 0; mt < 4; ++mt) {
#pragma unroll
      for (int r = 0; r < 4; ++r) {
        const int row = row0 + wm + mt * 16 + fq * 4 + r;
        Xg[(size_t)row * 4096 + pbase + fm] = f2bf(acc[mt][nt][r] + bv);
      }
    }
  }
}

// ---------------- Phase 2: persistent recurrence.
// 256 blocks: bn = blockIdx>>2 (hidden slice of 16), mi = blockIdx&3 (16 batch rows).
// Wave w holds Whh B-frags for its K-quarter in registers. c in registers.
// Barrier: per-mi-group (64 blocks), relaxed spin + single acquire load.
__global__ __launch_bounds__(256, 1) void lstm_seq(
    const unsigned short* __restrict__ Whh,  // [4096][1024] bf16
    const unsigned short* __restrict__ Xg,   // [32768][4096] bf16 permuted
    float* __restrict__ out,
    unsigned short* __restrict__ hbuf,       // 2 x [64][1024] bf16 ping-pong
    unsigned int* __restrict__ counters)     // 4 counters, 256B apart
{
  __shared__ float part[4][16][68];  // [wave][m][4*16 cols], +4 pad -> 2-way banks
  const int tid = threadIdx.x;
  const int lane = tid & 63;
  const int wave = tid >> 6;
  const int bn = blockIdx.x >> 2;
  const int mi = blockIdx.x & 3;
  const int fm = lane & 15;
  const int fq = lane >> 4;
  unsigned int* cnt = counters + mi * 64;  // one 256B line per group

  // Persistent B-frags: bfrag[gate][ki] = Whh[n][k], n=gate*1024+bn*16+fm,
  // k = wave*256 + ki*32 + fq*8 .. +8
  bf16x8 bfrag[4][8];
#pragma unroll
  for (int g = 0; g < 4; ++g) {
    const unsigned short* wrow =
        Whh + (size_t)(g * 1024 + bn * 16 + fm) * 1024 + wave * 256 + fq * 8;
#pragma unroll
    for (int ki = 0; ki < 8; ++ki) bfrag[g][ki] = *(const bf16x8*)(wrow + ki * 32);
  }

  const int em = tid >> 4, ej = tid & 15;   // elementwise: (batch-local, hidden-local)
  const int gb = mi * 16 + em;              // global batch row
  const int gj = bn * 16 + ej;              // global hidden index
  float c_reg = 0.f;

  unsigned short* h0 = hbuf;
  unsigned short* h1 = hbuf + BATCH * HID;

  // Prefetch Xg(0) into registers (constant data: survives barrier invalidates)
  const unsigned short* xrow = Xg + (size_t)gb * TSEQ * 4096 + bn * 64;
  float xpre[4];
#pragma unroll
  for (int g = 0; g < 4; ++g) xpre[g] = bf2f(xrow[g * 16 + ej]);

  for (int t = 0; t < TSEQ; ++t) {
    const unsigned short* hp = (t & 1) ? h1 : h0;
    unsigned short* hn = (t & 1) ? h0 : h1;

    f32x4 acc[4] = {};
    const unsigned short* ab =
        hp + (size_t)(mi * 16 + fm) * 1024 + wave * 256 + fq * 8;
#pragma unroll
    for (int ki = 0; ki < 8; ++ki) {
      bf16x8 a = *(const bf16x8*)(ab + ki * 32);
#pragma unroll
      for (int g = 0; g < 4; ++g)
        acc[g] = __builtin_amdgcn_mfma_f32_16x16x32_bf16(a, bfrag[g][ki], acc[g], 0, 0, 0);
    }
#pragma unroll
    for (int g = 0; g < 4; ++g)
#pragma unroll
      for (int r = 0; r < 4; ++r)
        part[wave][fq * 4 + r][g * 16 + fm] = acc[g][r];
    __syncthreads();

    // K-reduce over 4 waves + prefetched Xg + elementwise (1 (b,j) cell/thread)
    float gate[4];
#pragma unroll
    for (int g = 0; g < 4; ++g) {
      float s = part[0][em][g * 16 + ej] + part[1][em][g * 16 + ej] +
                part[2][em][g * 16 + ej] + part[3][em][g * 16 + ej];
      gate[g] = s + xpre[g];
    }
    const float ig = 1.f / (1.f + __expf(-gate[0]));
    const float fg = 1.f / (1.f + __expf(-gate[1]));
    const float gg = 1.f - 2.f / (__expf(2.f * gate[2]) + 1.f);  // tanh, inf-safe
    const float og = 1.f / (1.f + __expf(-gate[3]));
    c_reg = fg * c_reg + ig * gg;
    const float th = 1.f - 2.f / (__expf(2.f * c_reg) + 1.f);
    const float hv = og * th;

    hn[(size_t)gb * HID + gj] = f2bf(hv);
    out[((size_t)gb * TSEQ + t) * HID + gj] = hv;
    if (t == TSEQ - 1) {
      out[(size_t)BATCH * TSEQ * HID + (size_t)gb * HID + gj] = hv;
      out[(size_t)BATCH * TSEQ * HID + (size_t)BATCH * HID + (size_t)gb * HID + gj] = c_reg;
    } else {
      // Prefetch Xg(t+1) before the barrier (hidden under the spin wait)
      const unsigned short* xn = xrow + (size_t)(t + 1) * 4096;
#pragma unroll
      for (int g = 0; g < 4; ++g) xpre[g] = bf2f(xn[g * 16 + ej]);
    }

    // Group barrier: 64 blocks sharing mi. Release add (drains stores +
    // wbL2), relaxed spin (no cache ops), one acquire load (invL1/L2).
    __syncthreads();
    if (tid == 0) {
      __hip_atomic_fetch_add(cnt, 1u, __ATOMIC_RELEASE, __HIP_MEMORY_SCOPE_AGENT);
      const unsigned target = 64u * (unsigned)(t + 1);
      while (__hip_atomic_load(cnt, __ATOMIC_RELAXED, __HIP_MEMORY_SCOPE_AGENT) < target)
        __builtin_amdgcn_s_sleep(1);
      (void)__hip_atomic_load(cnt, __ATOMIC_ACQUIRE, __HIP_MEMORY_SCOPE_AGENT);
    }
    __syncthreads();
  }
}

extern "C" void kernel_launch(void* const* d_in, const int* in_sizes, int n_in,
                              void* d_out, int out_size, void* d_ws, size_t ws_size,
                              hipStream_t stream) {
  (void)in_sizes; (void)n_in; (void)out_size;
  const float* x   = (const float*)d_in[0];
  const float* Wih = (const float*)d_in[1];
  const float* Whh = (const float*)d_in[2];
  const float* b   = (const float*)d_in[3];
  float* out = (float*)d_out;

  char* ws = (char*)d_ws;
  unsigned int* counters = (unsigned int*)ws;                         // 1 KB (4 lines)
  unsigned short* hbuf   = (unsigned short*)(ws + 1024);              // 256 KB
  unsigned short* x_bf   = (unsigned short*)(ws + 263168);            // 64 MB
  unsigned short* wih_bf = (unsigned short*)(ws + 263168 + 67108864); // 8 MB
  unsigned short* whh_bf = (unsigned short*)(ws + 263168 + 75497472); // 8 MB
  unsigned short* xg     = (unsigned short*)(ws + 263168 + 83886080); // 256 MB
  const size_t needed = 263168ULL + 83886080ULL + 268435456ULL;       // ~337 MB
  if (ws_size < needed) return;  // fail visibly (zero output)

  hipMemsetAsync(counters, 0, 1024, stream);
  hipMemsetAsync(hbuf, 0, 2 * BATCH * HID * sizeof(unsigned short), stream);

  cvt_kernel<<<2048, 256, 0, stream>>>(x, x_bf, (MROWS * 1024) / 4);
  cvt_kernel<<<512, 256, 0, stream>>>(Wih, wih_bf, (NGATE * 1024) / 4);
  cvt_kernel<<<512, 256, 0, stream>>>(Whh, whh_bf, (NGATE * 1024) / 4);

  dim3 g(32, 256);  // (n-tiles, m-tiles)
  gemm_xg<<<g, 256, 0, stream>>>(x_bf, wih_bf, b, xg);

  lstm_seq<<<256, 256, 0, stream>>>(whh_bf, xg, out, hbuf, counters);
}